// Round 4
// baseline (181.006 us; speedup 1.0000x reference)
//
#include <hip/hip_runtime.h>
#include <hip/hip_fp16.h>

typedef _Float16 half8_t __attribute__((ext_vector_type(8)));
typedef float f32x4 __attribute__((ext_vector_type(4)));

__device__ __forceinline__ void gload_lds16(const void* g, void* l) {
    __builtin_amdgcn_global_load_lds(
        (const __attribute__((address_space(1))) void*)g,
        (__attribute__((address_space(3))) void*)l,
        16, 0, 0);
}

#define SBAR() asm volatile("s_barrier" ::: "memory")
#define LGKM0() asm volatile("s_waitcnt lgkmcnt(0)" ::: "memory")

template <int N> __device__ __forceinline__ void vm_wait();
template <> __device__ __forceinline__ void vm_wait<0>()  { asm volatile("s_waitcnt vmcnt(0)"  ::: "memory"); }
template <> __device__ __forceinline__ void vm_wait<4>()  { asm volatile("s_waitcnt vmcnt(4)"  ::: "memory"); }
template <> __device__ __forceinline__ void vm_wait<8>()  { asm volatile("s_waitcnt vmcnt(8)"  ::: "memory"); }
template <> __device__ __forceinline__ void vm_wait<12>() { asm volatile("s_waitcnt vmcnt(12)" ::: "memory"); }

// ---------------- PQ quantize only (x-cast now fused into GEMM) ----------
// pq v9 = v8 hot loop (4 VALU/score, lazy second-index recovery) + 4-batch
// amortization: each block owns 256 consecutive groups, stages the codebook
// fp16-split ONCE, then loops 4 batches of 64 groups (ghb/glb re-staged per
// batch behind a __syncthreads pair). Semantics identical to v8 per batch.
__global__ __launch_bounds__(256, 4) void pq_kernel(
    const float* __restrict__ W, const float* __restrict__ cbg,
    const float* __restrict__ rs, _Float16* __restrict__ wq,
    int groups_per_row) {
    __shared__ __align__(16) _Float16 cbh[256 * 8];  // fp16(-2c)
    __shared__ __align__(16) _Float16 cbl[256 * 8];  // fp16(-2c - cbh)
    __shared__ __align__(16) float    c2s[256];      // |c|^2
    __shared__ __align__(16) _Float16 ghb[64 * 8];   // fp16(g)
    __shared__ __align__(16) _Float16 glb[64 * 8];   // fp16(g - ghb)

    int tid = threadIdx.x;
    int bid = blockIdx.x;

    {   // stage codebook: thread k handles codeword k (once per block)
        const float4* cp4 = (const float4*)(cbg + tid * 8);
        float4 ca = cp4[0], cb4 = cp4[1];
        float cv[8] = {ca.x, ca.y, ca.z, ca.w, cb4.x, cb4.y, cb4.z, cb4.w};
        float c2 = 0.0f;
#pragma unroll
        for (int i = 0; i < 8; i++) {
            float c = cv[i];
            c2 = fmaf(c, c, c2);
            float m = -2.0f * c;
            _Float16 h = (_Float16)m;
            cbh[tid * 8 + i] = h;
            cbl[tid * 8 + i] = (_Float16)(m - (float)h);
        }
        c2s[tid] = c2;
    }

    int wave = tid >> 6, lane = tid & 63;
    int q = lane >> 4, n15 = lane & 15;
    const _Float16* asrc = (q & 1) ? cbl : cbh;   // quads 0,2: ch ; 1,3: cl
    const _Float16* gsrc = (q < 2) ? ghb : glb;   // quads 0,1: gh ; 2,3: gl

    for (int bt = 0; bt < 4; bt++) {
        int gblock = (bid * 4 + bt) * 64;
        float rsv = rs[gblock / groups_per_row];   // uniform: 64 | gpr
        float rinv = 1.0f / rsv;

        if (bt) __syncthreads();    // prior batch fully done reading ghb/glb
        {   // stage this batch's 64 groups (2 elems/thread, coalesced)
            const float* wp = W + (size_t)gblock * 8;
            float2 v2 = *(const float2*)(wp + tid * 2);
            float v0 = v2.x * rinv, v1 = v2.y * rinv;
            _Float16 h0 = (_Float16)v0, h1 = (_Float16)v1;
            ghb[tid * 2]     = h0;
            ghb[tid * 2 + 1] = h1;
            glb[tid * 2]     = (_Float16)(v0 - (float)h0);
            glb[tid * 2 + 1] = (_Float16)(v1 - (float)h1);
        }
        __syncthreads();

        // B-frag (groups): B[k=q*8+j][n]
        half8_t bfrag = *(const half8_t*)&gsrc[(wave * 16 + n15) * 8];

        float best = 1e30f, sec = 1e30f;
        int blc = 0;                // local code = t*16+r (literal cndmask)

#pragma unroll 4
        for (int t = 0; t < 16; t++) {
            half8_t afrag = *(const half8_t*)&asrc[(t * 16 + n15) * 8];
            f32x4 cc = *(const f32x4*)&c2s[t * 16 + q * 4];
            f32x4 d = __builtin_amdgcn_mfma_f32_16x16x32_f16(afrag, bfrag, cc, 0, 0, 0);
#pragma unroll
            for (int r = 0; r < 4; r++) {
                float s = d[r];
                bool lb = s < best;
                blc = lb ? (t * 16 + r) : blc;
                sec = __builtin_amdgcn_fmed3f(s, best, sec);   // sec w/ OLD best
                best = fminf(s, best);
            }
        }
        int bidx = blc + q * 4;
        int my_bidx = bidx;
        int sidx = -(q + 1);        // sentinel: "lane q's local sec"

        // merge the 4 quads — verbatim from v7/v8
#pragma unroll
        for (int mstep = 0; mstep < 2; mstep++) {
            int mask = 16 << mstep;
            float ob = __shfl_xor(best, mask, 64);
            float os = __shfl_xor(sec, mask, 64);
            int obi = __shfl_xor(bidx, mask, 64);
            int osi = __shfl_xor(sidx, mask, 64);
            bool sw = ob < best;
            float nb = fminf(best, ob);
            int nbi = sw ? obi : bidx;
            float m1 = fmaxf(best, ob);
            int m1i = sw ? bidx : obi;
            bool sw2 = os < sec;
            float m2 = fminf(sec, os);
            int m2i = sw2 ? osi : sidx;
            bool sw3 = m2 < m1;
            best = nb; bidx = nbi;
            sec = fminf(m1, m2);
            sidx = sw3 ? m2i : m1i;
        }

        // broadcast q0's canonical merged result to the 4-lane clique
        float gbest = __shfl(best, n15, 64);
        float gsec  = __shfl(sec,  n15, 64);
        int   gbi   = __shfl(bidx, n15, 64);
        int   gsi   = __shfl(sidx, n15, 64);
        bool trig = (gsec - gbest < 5e-4f);

        if (trig && gsi < 0) {      // rare: recover second-best index
            int qs = -gsi - 1;
            int found = -1;
#pragma unroll 4
            for (int t = 0; t < 16; t++) {
                half8_t afrag = *(const half8_t*)&asrc[(t * 16 + n15) * 8];
                f32x4 cc = *(const f32x4*)&c2s[t * 16 + q * 4];
                f32x4 d = __builtin_amdgcn_mfma_f32_16x16x32_f16(afrag, bfrag, cc, 0, 0, 0);
#pragma unroll
                for (int r = 0; r < 4; r++) {
                    int cw = t * 16 + q * 4 + r;
                    if (q == qs && found < 0 && d[r] == gsec && cw != my_bidx)
                        found = cw;
                }
            }
            found = max(found, __shfl_xor(found, 16, 64));
            found = max(found, __shfl_xor(found, 32, 64));
            gsi = (found < 0) ? gbi : found;
        }

        if (q == 0) {               // lanes 0-15 finalize one group each
            int g = gblock + wave * 16 + n15;
            int bi = gbi;
            if (trig) {
                const float* wp = W + (size_t)g * 8;
                const float* cbp = cbg + bi * 8;
                const float* csp = cbg + gsi * 8;
                double rsd = (double)rsv;
                double db = 0.0, ds = 0.0;
#pragma unroll
                for (int i = 0; i < 8; i++) {
                    double wd = (double)wp[i];
                    double d1 = fma(-rsd, (double)cbp[i], wd);
                    db = fma(d1, d1, db);
                    double d2_ = fma(-rsd, (double)csp[i], wd);
                    ds = fma(d2_, d2_, ds);
                }
                if (ds < db || (ds == db && gsi < bi)) bi = gsi;
            }
            const float* c = cbg + bi * 8;
            half8_t outv;
#pragma unroll
            for (int i = 0; i < 8; i++) outv[i] = (_Float16)(c[i] * rsv);
            *(half8_t*)(wq + (size_t)g * 8) = outv;
        }
    }
}

// ---------------- GEMM: C = x(fp32, cast on the fly) @ wq^T + bias ----------
// 128(M) x 256(N) tile, BK=64, full K, grid (8,32) = 256 blocks = 1/CU.
// v2: TWO phases per K-tile (16 MFMA each, 4 barriers/K-tile — template
// MFMA:barrier ratio). A is read as fp32 from x and RNE-cast (_Float16,
// identical to the old cvt kernel) during reg-staging, TWO K-tiles ahead
// (full-iteration latency cover), ds-written with the XOR swizzle. B keeps
// gload_lds with pre-swizzled global source.
//
// Issue order per iter kt:  P0: A-regs(kt+2) [4 glb]   P1: B(kt+2) [4 lds]
// Waits: mid-P1 vmcnt(12) -> A(kt+1) regs done (cvt+ds_write to other buf);
//        boundary vmcnt(8) -> B(kt+1) landed.  In-flight entering kt:
//        {A(kt+1) regs, B(kt+1)} = 8. Tail: {4,0}. Never 0 mid-loop.

__device__ __forceinline__ void stage_half(
    const _Float16* __restrict__ g, int K, int rowoff,
    _Float16* lt, int k0, int tid) {
#pragma unroll
    for (int l = 0; l < 2; ++l) {
        int u = l * 512 + tid;                 // 16B unit within half-tile
        int r = rowoff + (u >> 3);             // row in tile
        int ks = ((u & 7) ^ (r & 7)) << 3;     // source k offset (halfs)
        gload_lds16(g + (size_t)r * K + k0 + ks,
                    lt + (rowoff << 6) + ((l * 512 + (tid & ~63)) << 3));
    }
}

// swizzled LDS fragment read: element (r,k) lives at r*64 + (k ^ ((r&7)<<3))
__device__ __forceinline__ half8_t ldsr(const _Float16* t, int r, int k) {
    return *(const half8_t*)(t + r * 64 + (k ^ ((r & 7) << 3)));
}

__device__ __forceinline__ void gemm_step(
    int KT, int nkt, _Float16* smem, const float* __restrict__ Arowp,
    const _Float16* __restrict__ Bb, int K, int tid,
    int wm, int wn, int l15, int q8, int aw0, int aw1,
    f32x4 (&SL)[4], f32x4 (&SC)[4], f32x4 (&acc)[4][4]) {
    _Float16* At = smem + (KT & 1) * 24576;
    _Float16* Bt = At + 8192;
    _Float16* Ao = smem + ((KT + 1) & 1) * 24576;
    half8_t a[4][2], b[4][2];

    // ---- P0: all a, b[n0-1]; issue A-regs(kt+2) ----
#pragma unroll
    for (int mt = 0; mt < 4; mt++)
#pragma unroll
        for (int kk = 0; kk < 2; kk++)
            a[mt][kk] = ldsr(At, wm * 64 + mt * 16 + l15, kk * 32 + q8);
#pragma unroll
    for (int nt = 0; nt < 2; nt++)
#pragma unroll
        for (int kk = 0; kk < 2; kk++)
            b[nt][kk] = ldsr(Bt, wn * 64 + nt * 16 + l15, kk * 32 + q8);
    if (KT + 2 < nkt) {
        const float* p = Arowp + (size_t)(KT + 2) * 64;
#pragma unroll
        for (int l = 0; l < 4; l++) SL[l] = *(const f32x4*)(p + l * 4);
    }
    SBAR();
    __builtin_amdgcn_s_setprio(1);
#pragma unroll
    for (int mt = 0; mt < 4; mt++)
#pragma unroll
        for (int nt = 0; nt < 2; nt++)
#pragma unroll
            for (int kk = 0; kk < 2; kk++)
                acc[mt][nt] = __builtin_amdgcn_mfma_f32_16x16x32_f16(
                    a[mt][kk], b[nt][kk], acc[mt][nt], 0, 0, 0);
    __builtin_amdgcn_s_setprio(0);
    SBAR();

    // ---- P1: b[n2-3]; stage B(kt+2); cvt+write A(kt+1) ----
#pragma unroll
    for (int nt = 2; nt < 4; nt++)
#pragma unroll
        for (int kk = 0; kk < 2; kk++)
            b[nt][kk] = ldsr(Bt, wn * 64 + nt * 16 + l15, kk * 32 + q8);
    if (KT + 2 < nkt) {
        stage_half(Bb, K, 0,   Bt, (KT + 2) * 64, tid);
        stage_half(Bb, K, 128, Bt, (KT + 2) * 64, tid);
    }
    if (KT + 1 < nkt) {
        if (KT + 2 < nkt) vm_wait<12>(); else vm_wait<4>();
        half8_t h0, h1;
#pragma unroll
        for (int j = 0; j < 4; j++) {
            h0[j]     = (_Float16)SC[0][j];
            h0[4 + j] = (_Float16)SC[1][j];
            h1[j]     = (_Float16)SC[2][j];
            h1[4 + j] = (_Float16)SC[3][j];
        }
        *(half8_t*)(Ao + aw0) = h0;
        *(half8_t*)(Ao + aw1) = h1;
    }
    SBAR();
    __builtin_amdgcn_s_setprio(1);
#pragma unroll
    for (int mt = 0; mt < 4; mt++)
#pragma unroll
        for (int nt = 2; nt < 4; nt++)
#pragma unroll
            for (int kk = 0; kk < 2; kk++)
                acc[mt][nt] = __builtin_amdgcn_mfma_f32_16x16x32_f16(
                    a[mt][kk], b[nt][kk], acc[mt][nt], 0, 0, 0);
    __builtin_amdgcn_s_setprio(0);
    LGKM0();                        // A ds_writes visible before barrier
    if (KT + 2 < nkt)      vm_wait<8>();
    else if (KT + 1 < nkt) vm_wait<0>();
    SBAR();
}

__global__ __launch_bounds__(512, 2) void gemm_x_f16(
    const float* __restrict__ X, const _Float16* __restrict__ B,
    const float* __restrict__ bias, float* __restrict__ C,
    int M, int N, int K) {
    extern __shared__ __align__(16) _Float16 smem[];  // 2 x (A 16K + B 32K) = 96KB
    int tid = threadIdx.x;
    int wave = tid >> 6, lane = tid & 63;
    int wm = wave >> 2, wn = wave & 3;
    int l15 = lane & 15, q8 = (lane >> 4) * 8;
    int bn = blockIdx.x * 256, bm = blockIdx.y * 128;
    const _Float16* Bb = B + (size_t)bn * K;
    const int nkt = K / 64;

    // A-staging geometry: thread -> (row, 16-float chunk)
    int arow = tid >> 2, ac0 = (tid & 3) * 16;
    const float* Arowp = X + (size_t)(bm + arow) * K + ac0;
    int aw0 = arow * 64 + ((ac0)     ^ ((arow & 7) << 3));
    int aw1 = arow * 64 + ((ac0 + 8) ^ ((arow & 7) << 3));

    f32x4 sA0[4], sA1[4];
    f32x4 acc[4][4] = {};

    {   // prologue: A(0)->regs, B(0); A(1)->regs, B(1); cvt A(0); drain B(0)
        _Float16* A0b = smem;
        _Float16* B0b = smem + 8192;
        _Float16* B1b = smem + 24576 + 8192;
#pragma unroll
        for (int l = 0; l < 4; l++) sA0[l] = *(const f32x4*)(Arowp + l * 4);
        __builtin_amdgcn_sched_barrier(0);
        stage_half(Bb, K, 0,   B0b, 0, tid);
        stage_half(Bb, K, 128, B0b, 0, tid);
        __builtin_amdgcn_sched_barrier(0);
        if (nkt > 1) {
#pragma unroll
            for (int l = 0; l < 4; l++) sA1[l] = *(const f32x4*)(Arowp + 64 + l * 4);
            __builtin_amdgcn_sched_barrier(0);
            stage_half(Bb, K, 0,   B1b, 64, tid);
            stage_half(Bb, K, 128, B1b, 64, tid);
            __builtin_amdgcn_sched_barrier(0);
            vm_wait<12>();
        } else {
            vm_wait<0>();
        }
        {
            half8_t h0, h1;
#pragma unroll
            for (int j = 0; j < 4; j++) {
                h0[j]     = (_Float16)sA0[0][j];
                h0[4 + j] = (_Float16)sA0[1][j];
                h1[j]     = (_Float16)sA0[2][j];
                h1[4 + j] = (_Float16)sA0[3][j];
            }
            *(half8_t*)(A0b + aw0) = h0;
            *(half8_t*)(A0b + aw1) = h1;
        }
        if (nkt > 1) vm_wait<8>();
        LGKM0();
        SBAR();
    }

    for (int kt = 0; kt < nkt; kt += 2) {
        gemm_step(kt, nkt, smem, Arowp, Bb, K, tid, wm, wn, l15, q8,
                  aw0, aw1, sA0, sA1, acc);
        if (kt + 1 < nkt)
            gemm_step(kt + 1, nkt, smem, Arowp, Bb, K, tid, wm, wn, l15, q8,
                      aw0, aw1, sA1, sA0, acc);
    }

    int col_base = bn + wn * 64;
    int row_base = bm + wm * 64;
#pragma unroll
    for (int nt = 0; nt < 4; nt++) {
        int col = col_base + nt * 16 + l15;
        float bv = bias[col];
#pragma unroll
        for (int mt = 0; mt < 4; mt++) {
            int r0 = row_base + mt * 16 + (lane >> 4) * 4;
#pragma unroll
            for (int r = 0; r < 4; r++)
                C[(size_t)(r0 + r) * N + col] = acc[mt][nt][r] + bv;
        }
    }
}

extern "C" void kernel_launch(void* const* d_in, const int* in_sizes, int n_in,
                              void* d_out, int out_size, void* d_ws, size_t ws_size,
                              hipStream_t stream) {
    const float* x        = (const float*)d_in[0];
    const float* weight   = (const float*)d_in[1];
    const float* codebook = (const float*)d_in[2];
    const float* rowscale = (const float*)d_in[3];
    const float* bias     = (const float*)d_in[4];
    float* out = (float*)d_out;

    int O = in_sizes[3];          // row_scale has O elements
    int I = in_sizes[1] / O;      // weight is O*I
    int M = in_sizes[0] / I;      // x is (B*S)*I
    const int D = 8;
    int n_groups = O * I / D;

    _Float16* wq = (_Float16*)d_ws;   // only workspace now: O*I fp16

    static bool attr_set = false;
    if (!attr_set) {
        (void)hipFuncSetAttribute((const void*)gemm_x_f16,
                                  hipFuncAttributeMaxDynamicSharedMemorySize,
                                  98304);
        attr_set = true;
    }

    pq_kernel<<<n_groups / 256, 256, 0, stream>>>(
        weight, codebook, rowscale, wq, I / D);

    gemm_x_f16<<<dim3(O / 256, M / 128), 512, 98304, stream>>>(
        x, wq, bias, out, M, O, I);
}

// Round 7
// 162.709 us; speedup vs baseline: 1.1125x; 1.1125x over previous
//
#include <hip/hip_runtime.h>
#include <hip/hip_fp16.h>

typedef _Float16 half8_t __attribute__((ext_vector_type(8)));
typedef _Float16 half4_t __attribute__((ext_vector_type(4)));
typedef float f32x4 __attribute__((ext_vector_type(4)));

__device__ __forceinline__ void gload_lds16(const void* g, void* l) {
    __builtin_amdgcn_global_load_lds(
        (const __attribute__((address_space(1))) void*)g,
        (__attribute__((address_space(3))) void*)l,
        16, 0, 0);
}

#define SBAR() asm volatile("s_barrier" ::: "memory")
#define LGKM0() asm volatile("s_waitcnt lgkmcnt(0)" ::: "memory")

template <int N> __device__ __forceinline__ void vm_wait();
template <> __device__ __forceinline__ void vm_wait<0>() { asm volatile("s_waitcnt vmcnt(0)" ::: "memory"); }
template <> __device__ __forceinline__ void vm_wait<6>() { asm volatile("s_waitcnt vmcnt(6)" ::: "memory"); }

// ---------------- fused: PQ quantize (blocks [0,n_pq)) + x cast (rest) ----
// pq v9 hot path (4 VALU/score, lazy second-index recovery) + 4-batch
// codebook amortization (stage fp16-split codebook once per 256 groups).
// cvt tail blocks restored (fp32->fp16 x cast; GEMM A reads fp16 again —
// round-4 proved fp32-A fetch duplication costs more than the cvt pass).
__global__ __launch_bounds__(256, 4) void pq_cvt_kernel(
    const float* __restrict__ W, const float* __restrict__ cbg,
    const float* __restrict__ rs, _Float16* __restrict__ wq,
    const float* __restrict__ x, _Float16* __restrict__ xh,
    int n_x, int groups_per_row, int n_pq_blocks) {
    __shared__ __align__(16) _Float16 cbh[256 * 8];  // fp16(-2c)
    __shared__ __align__(16) _Float16 cbl[256 * 8];  // fp16(-2c - cbh)
    __shared__ __align__(16) float    c2s[256];      // |c|^2
    __shared__ __align__(16) _Float16 ghb[64 * 8];   // fp16(g)
    __shared__ __align__(16) _Float16 glb[64 * 8];   // fp16(g - ghb)

    int tid = threadIdx.x;
    int bid = blockIdx.x;

    if (bid >= n_pq_blocks) {           // ---- cvt part ----
        int i = ((bid - n_pq_blocks) * 256 + tid) * 4;
        if (i < n_x) {
            float4 v = *(const float4*)(x + i);
            half4_t h;
            h[0] = (_Float16)v.x; h[1] = (_Float16)v.y;
            h[2] = (_Float16)v.z; h[3] = (_Float16)v.w;
            *(half4_t*)(xh + i) = h;
        }
        return;
    }

    {   // stage codebook: thread k handles codeword k (once per block)
        const float4* cp4 = (const float4*)(cbg + tid * 8);
        float4 ca = cp4[0], cb4 = cp4[1];
        float cv[8] = {ca.x, ca.y, ca.z, ca.w, cb4.x, cb4.y, cb4.z, cb4.w};
        float c2 = 0.0f;
#pragma unroll
        for (int i = 0; i < 8; i++) {
            float c = cv[i];
            c2 = fmaf(c, c, c2);
            float m = -2.0f * c;
            _Float16 h = (_Float16)m;
            cbh[tid * 8 + i] = h;
            cbl[tid * 8 + i] = (_Float16)(m - (float)h);
        }
        c2s[tid] = c2;
    }

    int wave = tid >> 6, lane = tid & 63;
    int q = lane >> 4, n15 = lane & 15;
    const _Float16* asrc = (q & 1) ? cbl : cbh;   // quads 0,2: ch ; 1,3: cl
    const _Float16* gsrc = (q < 2) ? ghb : glb;   // quads 0,1: gh ; 2,3: gl

    for (int bt = 0; bt < 4; bt++) {
        int gblock = (bid * 4 + bt) * 64;
        float rsv = rs[gblock / groups_per_row];   // uniform: 64 | gpr
        float rinv = 1.0f / rsv;

        if (bt) __syncthreads();    // prior batch fully done reading ghb/glb
        {   // stage this batch's 64 groups (2 elems/thread, coalesced)
            const float* wp = W + (size_t)gblock * 8;
            float2 v2 = *(const float2*)(wp + tid * 2);
            float v0 = v2.x * rinv, v1 = v2.y * rinv;
            _Float16 h0 = (_Float16)v0, h1 = (_Float16)v1;
            ghb[tid * 2]     = h0;
            ghb[tid * 2 + 1] = h1;
            glb[tid * 2]     = (_Float16)(v0 - (float)h0);
            glb[tid * 2 + 1] = (_Float16)(v1 - (float)h1);
        }
        __syncthreads();

        // B-frag (groups): B[k=q*8+j][n]
        half8_t bfrag = *(const half8_t*)&gsrc[(wave * 16 + n15) * 8];

        float best = 1e30f, sec = 1e30f;
        int blc = 0;                // local code = t*16+r (literal cndmask)

#pragma unroll 4
        for (int t = 0; t < 16; t++) {
            half8_t afrag = *(const half8_t*)&asrc[(t * 16 + n15) * 8];
            f32x4 cc = *(const f32x4*)&c2s[t * 16 + q * 4];
            f32x4 d = __builtin_amdgcn_mfma_f32_16x16x32_f16(afrag, bfrag, cc, 0, 0, 0);
#pragma unroll
            for (int r = 0; r < 4; r++) {
                float s = d[r];
                bool lb = s < best;
                blc = lb ? (t * 16 + r) : blc;
                sec = __builtin_amdgcn_fmed3f(s, best, sec);   // sec w/ OLD best
                best = fminf(s, best);
            }
        }
        int bidx = blc + q * 4;
        int my_bidx = bidx;
        int sidx = -(q + 1);        // sentinel: "lane q's local sec"

        // merge the 4 quads — verbatim from v7/v8
#pragma unroll
        for (int mstep = 0; mstep < 2; mstep++) {
            int mask = 16 << mstep;
            float ob = __shfl_xor(best, mask, 64);
            float os = __shfl_xor(sec, mask, 64);
            int obi = __shfl_xor(bidx, mask, 64);
            int osi = __shfl_xor(sidx, mask, 64);
            bool sw = ob < best;
            float nb = fminf(best, ob);
            int nbi = sw ? obi : bidx;
            float m1 = fmaxf(best, ob);
            int m1i = sw ? bidx : obi;
            bool sw2 = os < sec;
            float m2 = fminf(sec, os);
            int m2i = sw2 ? osi : sidx;
            bool sw3 = m2 < m1;
            best = nb; bidx = nbi;
            sec = fminf(m1, m2);
            sidx = sw3 ? m2i : m1i;
        }

        // broadcast q0's canonical merged result to the 4-lane clique
        float gbest = __shfl(best, n15, 64);
        float gsec  = __shfl(sec,  n15, 64);
        int   gbi   = __shfl(bidx, n15, 64);
        int   gsi   = __shfl(sidx, n15, 64);
        bool trig = (gsec - gbest < 5e-4f);

        if (trig && gsi < 0) {      // rare: recover second-best index
            int qs = -gsi - 1;
            int found = -1;
#pragma unroll 4
            for (int t = 0; t < 16; t++) {
                half8_t afrag = *(const half8_t*)&asrc[(t * 16 + n15) * 8];
                f32x4 cc = *(const f32x4*)&c2s[t * 16 + q * 4];
                f32x4 d = __builtin_amdgcn_mfma_f32_16x16x32_f16(afrag, bfrag, cc, 0, 0, 0);
#pragma unroll
                for (int r = 0; r < 4; r++) {
                    int cw = t * 16 + q * 4 + r;
                    if (q == qs && found < 0 && d[r] == gsec && cw != my_bidx)
                        found = cw;
                }
            }
            found = max(found, __shfl_xor(found, 16, 64));
            found = max(found, __shfl_xor(found, 32, 64));
            gsi = (found < 0) ? gbi : found;
        }

        if (q == 0) {               // lanes 0-15 finalize one group each
            int g = gblock + wave * 16 + n15;
            int bi = gbi;
            if (trig) {
                const float* wp = W + (size_t)g * 8;
                const float* cbp = cbg + bi * 8;
                const float* csp = cbg + gsi * 8;
                double rsd = (double)rsv;
                double db = 0.0, ds = 0.0;
#pragma unroll
                for (int i = 0; i < 8; i++) {
                    double wd = (double)wp[i];
                    double d1 = fma(-rsd, (double)cbp[i], wd);
                    db = fma(d1, d1, db);
                    double d2_ = fma(-rsd, (double)csp[i], wd);
                    ds = fma(d2_, d2_, ds);
                }
                if (ds < db || (ds == db && gsi < bi)) bi = gsi;
            }
            const float* c = cbg + bi * 8;
            half8_t outv;
#pragma unroll
            for (int i = 0; i < 8; i++) outv[i] = (_Float16)(c[i] * rsv);
            *(half8_t*)(wq + (size_t)g * 8) = outv;
        }
    }
}

// ---------------- GEMM: C[M][N] = A[M][K] @ B[N][K]^T (+ bias) ----------------
// 128(M) x 256(N) tile, BK=64, full K, 256 blocks = 1/CU, 8 waves (2Mx4N).
// v3: TWO phases per K-tile, 3 barriers/K-tile, both operands fp16 via
// gload_lds (linear dest + inverse-swizzled source), boundary vmcnt(6).
//
// Per K-tile kt (kt+2 shares LDS parity with kt):
//   16 ds_read (all a, all b) ; lgkmcnt(0) ; SBAR#1
//     -> barrier certifies ALL waves consumed buffers => overwrite-safe
//   stage A(kt+2)[2] + Blo(kt+2)[2] into current bufs ; 16 MFMA (b0-1) ; SBAR#2
//   stage Bhi(kt+2)[2] ; 16 MFMA (b2-3) ; vmcnt(6) ; SBAR#3
// In-flight entering kt: {A,B}(kt+1) = 6. Never drained to 0 mid-loop.
//
// XCD swizzle: grid is (M/128=32) x (N/256=8) blocks; HW assigns XCD by
// (linear id % 8). We decode 1D ids so each XCD owns an 8(M)x4(N) rect:
// A-panel dup x2, B-panel dup x4 (cost-optimal for fp16 A / fp16 B sizes).

__device__ __forceinline__ void stage_half(
    const _Float16* __restrict__ g, int K, int rowoff,
    _Float16* lt, int k0, int tid) {
#pragma unroll
    for (int l = 0; l < 2; ++l) {
        int u = l * 512 + tid;                 // 16B unit within half-tile
        int r = rowoff + (u >> 3);             // row in tile
        int ks = ((u & 7) ^ (r & 7)) << 3;     // source k offset (halfs)
        gload_lds16(g + (size_t)r * K + k0 + ks,
                    lt + (rowoff << 6) + ((l * 512 + (tid & ~63)) << 3));
    }
}

// swizzled LDS fragment read: element (r,k) lives at r*64 + (k ^ ((r&7)<<3))
__device__ __forceinline__ half8_t ldsr(const _Float16* t, int r, int k) {
    return *(const half8_t*)(t + r * 64 + (k ^ ((r & 7) << 3)));
}

__global__ __launch_bounds__(512, 2) void gemm_f16_v3(
    const _Float16* __restrict__ A, const _Float16* __restrict__ B,
    const float* __restrict__ bias, float* __restrict__ C,
    int M, int N, int K) {
    extern __shared__ __align__(16) _Float16 smem[];  // 2 x (A 8192 | B 16384) halfs
    int tid = threadIdx.x;
    int wave = tid >> 6, lane = tid & 63;
    int wm = wave >> 2, wn = wave & 3;
    int l15 = lane & 15, q8 = (lane >> 4) * 8;

    int nbm = M >> 7, nbn = N >> 8;
    int bid = blockIdx.x, mb, nb;
    if (nbm == 32 && nbn == 8) {        // 8x4 rect per XCD (bijective)
        int r = bid & 7, w = bid >> 3;
        mb = (r & 3) * 8 + (w & 7);
        nb = (r >> 2) * 4 + (w >> 3);
    } else {                            // fallback: plain decode
        nb = bid % nbn; mb = bid / nbn;
    }
    int bm = mb * 128, bn = nb * 256;
    const _Float16* Ab = A + (size_t)bm * K;
    const _Float16* Bb = B + (size_t)bn * K;
    const int nkt = K / 64;

    f32x4 acc[4][4] = {};

    {   // prologue: stage {A,B}(0) then {A,B}(1); drain kt0's 6
        _Float16* A0 = smem;
        _Float16* B0 = smem + 8192;
        _Float16* A1 = smem + 24576;
        _Float16* B1 = A1 + 8192;
        stage_half(Ab, K, 0,   A0, 0, tid);
        stage_half(Bb, K, 0,   B0, 0, tid);
        stage_half(Bb, K, 128, B0, 0, tid);
        asm volatile("" ::: "memory");   // pin kt0/kt1 issue order
        if (nkt > 1) {
            stage_half(Ab, K, 0,   A1, 64, tid);
            stage_half(Bb, K, 0,   B1, 64, tid);
            stage_half(Bb, K, 128, B1, 64, tid);
            vm_wait<6>();
        } else {
            vm_wait<0>();
        }
        SBAR();
    }

    for (int kt = 0; kt < nkt; ++kt) {
        _Float16* At = smem + (kt & 1) * 24576;
        _Float16* Bt = At + 8192;
        int k2 = (kt + 2) * 64;
        half8_t a[4][2], b[4][2];

        // ---- all fragment reads for this K-tile ----
#pragma unroll
        for (int mt = 0; mt < 4; mt++)
#pragma unroll
            for (int kk = 0; kk < 2; kk++)
                a[mt][kk] = ldsr(At, wm * 64 + mt * 16 + l15, kk * 32 + q8);
#pragma unroll
        for (int nt = 0; nt < 4; nt++)
#pragma unroll
            for (int kk = 0; kk < 2; kk++)
                b[nt][kk] = ldsr(Bt, wn * 64 + nt * 16 + l15, kk * 32 + q8);
        LGKM0();                 // own reads complete before barrier
        SBAR();                  // => ALL waves done reading At/Bt

        // ---- P0: stage A(kt+2)+Blo(kt+2) into dead current bufs; MFMA b0-1
        if (kt + 2 < nkt) {
            stage_half(Ab, K, 0, At, k2, tid);
            stage_half(Bb, K, 0, Bt, k2, tid);
        }
        __builtin_amdgcn_s_setprio(1);
#pragma unroll
        for (int mt = 0; mt < 4; mt++)
#pragma unroll
            for (int nt = 0; nt < 2; nt++)
#pragma unroll
                for (int kk = 0; kk < 2; kk++)
                    acc[mt][nt] = __builtin_amdgcn_mfma_f32_16x16x32_f16(
                        a[mt][kk], b[nt][kk], acc[mt][nt], 0, 0, 0);
        __builtin_amdgcn_s_setprio(0);
        SBAR();

        // ---- P1: stage Bhi(kt+2); MFMA b2-3; boundary wait ----
        if (kt + 2 < nkt)
            stage_half(Bb, K, 128, Bt, k2, tid);
        __builtin_amdgcn_s_setprio(1);
#pragma unroll
        for (int mt = 0; mt < 4; mt++)
#pragma unroll
            for (int nt = 2; nt < 4; nt++)
#pragma unroll
                for (int kk = 0; kk < 2; kk++)
                    acc[mt][nt] = __builtin_amdgcn_mfma_f32_16x16x32_f16(
                        a[mt][kk], b[nt][kk], acc[mt][nt], 0, 0, 0);
        __builtin_amdgcn_s_setprio(0);
        if (kt + 2 < nkt)      vm_wait<6>();
        else if (kt + 1 < nkt) vm_wait<0>();
        SBAR();
    }

    int col_base = bn + wn * 64;
    int row_base = bm + wm * 64;
#pragma unroll
    for (int nt = 0; nt < 4; nt++) {
        int col = col_base + nt * 16 + l15;
        float bv = bias[col];
#pragma unroll
        for (int mt = 0; mt < 4; mt++) {
            int r0 = row_base + mt * 16 + (lane >> 4) * 4;
#pragma unroll
            for (int r = 0; r < 4; r++)
                C[(size_t)(r0 + r) * N + col] = acc[mt][nt][r] + bv;
        }
    }
}

extern "C" void kernel_launch(void* const* d_in, const int* in_sizes, int n_in,
                              void* d_out, int out_size, void* d_ws, size_t ws_size,
                              hipStream_t stream) {
    const float* x        = (const float*)d_in[0];
    const float* weight   = (const float*)d_in[1];
    const float* codebook = (const float*)d_in[2];
    const float* rowscale = (const float*)d_in[3];
    const float* bias     = (const float*)d_in[4];
    float* out = (float*)d_out;

    int O = in_sizes[3];          // row_scale has O elements
    int I = in_sizes[1] / O;      // weight is O*I
    int M = in_sizes[0] / I;      // x is (B*S)*I
    const int D = 8;
    int n_groups = O * I / D;

    size_t off = 0;
    _Float16* xh = (_Float16*)d_ws;                off += (size_t)M * I * sizeof(_Float16);
    _Float16* wq = (_Float16*)((char*)d_ws + off);

    static bool attr_set = false;
    if (!attr_set) {
        (void)hipFuncSetAttribute((const void*)gemm_f16_v3,
                                  hipFuncAttributeMaxDynamicSharedMemorySize,
                                  98304);
        attr_set = true;
    }

    int n_x = M * I;
    int n_pq_blocks = n_groups / 256;
    int n_cvt_blocks = (n_x / 4 + 255) / 256;
    pq_cvt_kernel<<<n_pq_blocks + n_cvt_blocks, 256, 0, stream>>>(
        weight, codebook, rowscale, wq, x, xh, n_x, I / D, n_pq_blocks);

    gemm_f16_v3<<<(M / 128) * (O / 256), 512, 98304, stream>>>(
        xh, wq, bias, out, M, O, I);
}

// Round 8
// 157.183 us; speedup vs baseline: 1.1516x; 1.0352x over previous
//
#include <hip/hip_runtime.h>
#include <hip/hip_fp16.h>

typedef _Float16 half8_t __attribute__((ext_vector_type(8)));
typedef _Float16 half4_t __attribute__((ext_vector_type(4)));
typedef float f32x4 __attribute__((ext_vector_type(4)));

__device__ __forceinline__ void gload_lds16(const void* g, void* l) {
    __builtin_amdgcn_global_load_lds(
        (const __attribute__((address_space(1))) void*)g,
        (__attribute__((address_space(3))) void*)l,
        16, 0, 0);
}

#define SBAR() asm volatile("s_barrier" ::: "memory")
#define LGKM0() asm volatile("s_waitcnt lgkmcnt(0)" ::: "memory")

template <int N> __device__ __forceinline__ void vm_wait();
template <> __device__ __forceinline__ void vm_wait<0>() { asm volatile("s_waitcnt vmcnt(0)" ::: "memory"); }
template <> __device__ __forceinline__ void vm_wait<8>() { asm volatile("s_waitcnt vmcnt(8)" ::: "memory"); }

// ---------------- fused: PQ quantize (blocks [0,n_pq)) + x cast (rest) ----
// pq v9 (UNCHANGED from round-7 measured baseline): 4 VALU/score hot loop,
// lazy second-index recovery, 4-batch codebook amortization, cvt tail.
__global__ __launch_bounds__(256, 4) void pq_cvt_kernel(
    const float* __restrict__ W, const float* __restrict__ cbg,
    const float* __restrict__ rs, _Float16* __restrict__ wq,
    const float* __restrict__ x, _Float16* __restrict__ xh,
    int n_x, int groups_per_row, int n_pq_blocks) {
    __shared__ __align__(16) _Float16 cbh[256 * 8];  // fp16(-2c)
    __shared__ __align__(16) _Float16 cbl[256 * 8];  // fp16(-2c - cbh)
    __shared__ __align__(16) float    c2s[256];      // |c|^2
    __shared__ __align__(16) _Float16 ghb[64 * 8];   // fp16(g)
    __shared__ __align__(16) _Float16 glb[64 * 8];   // fp16(g - ghb)

    int tid = threadIdx.x;
    int bid = blockIdx.x;

    if (bid >= n_pq_blocks) {           // ---- cvt part ----
        int i = ((bid - n_pq_blocks) * 256 + tid) * 4;
        if (i < n_x) {
            float4 v = *(const float4*)(x + i);
            half4_t h;
            h[0] = (_Float16)v.x; h[1] = (_Float16)v.y;
            h[2] = (_Float16)v.z; h[3] = (_Float16)v.w;
            *(half4_t*)(xh + i) = h;
        }
        return;
    }

    {   // stage codebook: thread k handles codeword k (once per block)
        const float4* cp4 = (const float4*)(cbg + tid * 8);
        float4 ca = cp4[0], cb4 = cp4[1];
        float cv[8] = {ca.x, ca.y, ca.z, ca.w, cb4.x, cb4.y, cb4.z, cb4.w};
        float c2 = 0.0f;
#pragma unroll
        for (int i = 0; i < 8; i++) {
            float c = cv[i];
            c2 = fmaf(c, c, c2);
            float m = -2.0f * c;
            _Float16 h = (_Float16)m;
            cbh[tid * 8 + i] = h;
            cbl[tid * 8 + i] = (_Float16)(m - (float)h);
        }
        c2s[tid] = c2;
    }

    int wave = tid >> 6, lane = tid & 63;
    int q = lane >> 4, n15 = lane & 15;
    const _Float16* asrc = (q & 1) ? cbl : cbh;   // quads 0,2: ch ; 1,3: cl
    const _Float16* gsrc = (q < 2) ? ghb : glb;   // quads 0,1: gh ; 2,3: gl

    for (int bt = 0; bt < 4; bt++) {
        int gblock = (bid * 4 + bt) * 64;
        float rsv = rs[gblock / groups_per_row];   // uniform: 64 | gpr
        float rinv = 1.0f / rsv;

        if (bt) __syncthreads();    // prior batch fully done reading ghb/glb
        {   // stage this batch's 64 groups (2 elems/thread, coalesced)
            const float* wp = W + (size_t)gblock * 8;
            float2 v2 = *(const float2*)(wp + tid * 2);
            float v0 = v2.x * rinv, v1 = v2.y * rinv;
            _Float16 h0 = (_Float16)v0, h1 = (_Float16)v1;
            ghb[tid * 2]     = h0;
            ghb[tid * 2 + 1] = h1;
            glb[tid * 2]     = (_Float16)(v0 - (float)h0);
            glb[tid * 2 + 1] = (_Float16)(v1 - (float)h1);
        }
        __syncthreads();

        // B-frag (groups): B[k=q*8+j][n]
        half8_t bfrag = *(const half8_t*)&gsrc[(wave * 16 + n15) * 8];

        float best = 1e30f, sec = 1e30f;
        int blc = 0;                // local code = t*16+r (literal cndmask)

#pragma unroll 4
        for (int t = 0; t < 16; t++) {
            half8_t afrag = *(const half8_t*)&asrc[(t * 16 + n15) * 8];
            f32x4 cc = *(const f32x4*)&c2s[t * 16 + q * 4];
            f32x4 d = __builtin_amdgcn_mfma_f32_16x16x32_f16(afrag, bfrag, cc, 0, 0, 0);
#pragma unroll
            for (int r = 0; r < 4; r++) {
                float s = d[r];
                bool lb = s < best;
                blc = lb ? (t * 16 + r) : blc;
                sec = __builtin_amdgcn_fmed3f(s, best, sec);   // sec w/ OLD best
                best = fminf(s, best);
            }
        }
        int bidx = blc + q * 4;
        int my_bidx = bidx;
        int sidx = -(q + 1);        // sentinel: "lane q's local sec"

        // merge the 4 quads — verbatim from v7/v8
#pragma unroll
        for (int mstep = 0; mstep < 2; mstep++) {
            int mask = 16 << mstep;
            float ob = __shfl_xor(best, mask, 64);
            float os = __shfl_xor(sec, mask, 64);
            int obi = __shfl_xor(bidx, mask, 64);
            int osi = __shfl_xor(sidx, mask, 64);
            bool sw = ob < best;
            float nb = fminf(best, ob);
            int nbi = sw ? obi : bidx;
            float m1 = fmaxf(best, ob);
            int m1i = sw ? bidx : obi;
            bool sw2 = os < sec;
            float m2 = fminf(sec, os);
            int m2i = sw2 ? osi : sidx;
            bool sw3 = m2 < m1;
            best = nb; bidx = nbi;
            sec = fminf(m1, m2);
            sidx = sw3 ? m2i : m1i;
        }

        // broadcast q0's canonical merged result to the 4-lane clique
        float gbest = __shfl(best, n15, 64);
        float gsec  = __shfl(sec,  n15, 64);
        int   gbi   = __shfl(bidx, n15, 64);
        int   gsi   = __shfl(sidx, n15, 64);
        bool trig = (gsec - gbest < 5e-4f);

        if (trig && gsi < 0) {      // rare: recover second-best index
            int qs = -gsi - 1;
            int found = -1;
#pragma unroll 4
            for (int t = 0; t < 16; t++) {
                half8_t afrag = *(const half8_t*)&asrc[(t * 16 + n15) * 8];
                f32x4 cc = *(const f32x4*)&c2s[t * 16 + q * 4];
                f32x4 d = __builtin_amdgcn_mfma_f32_16x16x32_f16(afrag, bfrag, cc, 0, 0, 0);
#pragma unroll
                for (int r = 0; r < 4; r++) {
                    int cw = t * 16 + q * 4 + r;
                    if (q == qs && found < 0 && d[r] == gsec && cw != my_bidx)
                        found = cw;
                }
            }
            found = max(found, __shfl_xor(found, 16, 64));
            found = max(found, __shfl_xor(found, 32, 64));
            gsi = (found < 0) ? gbi : found;
        }

        if (q == 0) {               // lanes 0-15 finalize one group each
            int g = gblock + wave * 16 + n15;
            int bi = gbi;
            if (trig) {
                const float* wp = W + (size_t)g * 8;
                const float* cbp = cbg + bi * 8;
                const float* csp = cbg + gsi * 8;
                double rsd = (double)rsv;
                double db = 0.0, ds = 0.0;
#pragma unroll
                for (int i = 0; i < 8; i++) {
                    double wd = (double)wp[i];
                    double d1 = fma(-rsd, (double)cbp[i], wd);
                    db = fma(d1, d1, db);
                    double d2_ = fma(-rsd, (double)csp[i], wd);
                    ds = fma(d2_, d2_, ds);
                }
                if (ds < db || (ds == db && gsi < bi)) bi = gsi;
            }
            const float* c = cbg + bi * 8;
            half8_t outv;
#pragma unroll
            for (int i = 0; i < 8; i++) outv[i] = (_Float16)(c[i] * rsv);
            *(half8_t*)(wq + (size_t)g * 8) = outv;
        }
    }
}

// ---------------- GEMM: C[M][N] = A[M][K] @ B[N][K]^T (+ bias) ----------------
// v4: 128x128 tile, BK=64, 256 threads (4 waves 2x2, 64x64 each), 64 KiB
// LDS double-buffer => TWO blocks resident per CU. Same v3 pipeline
// (certify-barrier, stage kt+2 into current buffers, counted boundary
// vm_wait<8>, never 0 mid-loop). Rationale: v3's all-reads-then-lgkm0
// structure serializes the LDS pipe against the MFMA pipe across the whole
// block (measured 26% MfmaUtil @ 1 block/CU); a co-resident block fills
// those phase stalls.
//
// Per K-tile kt (kt+2 shares LDS parity with kt):
//   16 ds_read (all a,b) ; lgkmcnt(0) ; SBAR#1  -> buffers consumed
//   stage A(kt+2)+B(kt+2) [8 loads] into current bufs ; 32 MFMA
//   vmcnt(8) (drains kt+1, keeps kt+2 in flight) ; SBAR#2
//
// XCD swizzle: grid 32(M) x 16(N); 1D id decoded so each XCD owns an
// 8(M)x8(N) rect (XCDs in 4x2 arrangement: A-panel dup x2, B-panel dup x4).

__device__ __forceinline__ void stage_tile(
    const _Float16* __restrict__ g, int K, _Float16* lt, int k0, int tid) {
#pragma unroll
    for (int l = 0; l < 4; ++l) {
        int u = l * 256 + tid;                 // 16B unit, 1024 per 128x64 tile
        int r = u >> 3;                        // row 0..127
        int ks = ((u & 7) ^ (r & 7)) << 3;     // inverse-swizzled source k
        gload_lds16(g + (size_t)r * K + k0 + ks,
                    lt + ((l * 256 + (tid & ~63)) << 3));
    }
}

// swizzled LDS fragment read: element (r,k) lives at r*64 + (k ^ ((r&7)<<3))
__device__ __forceinline__ half8_t ldsr(const _Float16* t, int r, int k) {
    return *(const half8_t*)(t + r * 64 + (k ^ ((r & 7) << 3)));
}

__global__ __launch_bounds__(256, 2) void gemm_f16_v4(
    const _Float16* __restrict__ A, const _Float16* __restrict__ B,
    const float* __restrict__ bias, float* __restrict__ C,
    int M, int N, int K) {
    extern __shared__ __align__(16) _Float16 smem[];  // 2 x (A 8192 | B 8192)
    int tid = threadIdx.x;
    int wave = tid >> 6, lane = tid & 63;
    int wm = wave >> 1, wn = wave & 1;
    int l15 = lane & 15, q8 = (lane >> 4) * 8;

    int nbm = M >> 7, nbn = N >> 7;
    int bid = blockIdx.x, mb, nb;
    if (nbm == 32 && nbn == 16) {       // 8x8 rect per XCD (bijective)
        int x = bid & 7, w = bid >> 3;  // w in [0,64)
        mb = (x & 3) * 8 + (w & 7);
        nb = (x >> 2) * 8 + (w >> 3);
    } else {                            // fallback: plain decode
        nb = bid % nbn; mb = bid / nbn;
    }
    int bm = mb * 128, bn = nb * 128;
    const _Float16* Ab = A + (size_t)bm * K;
    const _Float16* Bb = B + (size_t)bn * K;
    const int nkt = K / 64;

    f32x4 acc[4][4] = {};

    {   // prologue: stage {A,B}(0) into buf0, {A,B}(1) into buf1; drain kt0
        stage_tile(Ab, K, smem,          0,  tid);
        stage_tile(Bb, K, smem + 8192,   0,  tid);
        __builtin_amdgcn_sched_barrier(0);   // pin kt0/kt1 issue order
        if (nkt > 1) {
            stage_tile(Ab, K, smem + 16384, 64, tid);
            stage_tile(Bb, K, smem + 24576, 64, tid);
            vm_wait<8>();
        } else {
            vm_wait<0>();
        }
        SBAR();
    }

    for (int kt = 0; kt < nkt; ++kt) {
        _Float16* At = smem + (kt & 1) * 16384;
        _Float16* Bt = At + 8192;
        int k2 = (kt + 2) * 64;
        half8_t a[4][2], b[4][2];

        // ---- all fragment reads for this K-tile ----
#pragma unroll
        for (int mt = 0; mt < 4; mt++)
#pragma unroll
            for (int kk = 0; kk < 2; kk++)
                a[mt][kk] = ldsr(At, wm * 64 + mt * 16 + l15, kk * 32 + q8);
#pragma unroll
        for (int nt = 0; nt < 4; nt++)
#pragma unroll
            for (int kk = 0; kk < 2; kk++)
                b[nt][kk] = ldsr(Bt, wn * 64 + nt * 16 + l15, kk * 32 + q8);
        LGKM0();                 // own reads complete before barrier
        SBAR();                  // => ALL waves done reading At/Bt

        // ---- stage kt+2 into the (now dead) current buffers; 32 MFMA ----
        if (kt + 2 < nkt) {
            stage_tile(Ab, K, At, k2, tid);
            stage_tile(Bb, K, Bt, k2, tid);
        }
        __builtin_amdgcn_s_setprio(1);
#pragma unroll
        for (int mt = 0; mt < 4; mt++)
#pragma unroll
            for (int nt = 0; nt < 4; nt++)
#pragma unroll
                for (int kk = 0; kk < 2; kk++)
                    acc[mt][nt] = __builtin_amdgcn_mfma_f32_16x16x32_f16(
                        a[mt][kk], b[nt][kk], acc[mt][nt], 0, 0, 0);
        __builtin_amdgcn_s_setprio(0);
        if (kt + 2 < nkt)      vm_wait<8>();   // drain kt+1, keep kt+2 in flight
        else if (kt + 1 < nkt) vm_wait<0>();
        SBAR();
    }

    int col_base = bn + wn * 64;
    int row_base = bm + wm * 64;
#pragma unroll
    for (int nt = 0; nt < 4; nt++) {
        int col = col_base + nt * 16 + l15;
        float bv = bias[col];
#pragma unroll
        for (int mt = 0; mt < 4; mt++) {
            int r0 = row_base + mt * 16 + (lane >> 4) * 4;
#pragma unroll
            for (int r = 0; r < 4; r++)
                C[(size_t)(r0 + r) * N + col] = acc[mt][nt][r] + bv;
        }
    }
}

extern "C" void kernel_launch(void* const* d_in, const int* in_sizes, int n_in,
                              void* d_out, int out_size, void* d_ws, size_t ws_size,
                              hipStream_t stream) {
    const float* x        = (const float*)d_in[0];
    const float* weight   = (const float*)d_in[1];
    const float* codebook = (const float*)d_in[2];
    const float* rowscale = (const float*)d_in[3];
    const float* bias     = (const float*)d_in[4];
    float* out = (float*)d_out;

    int O = in_sizes[3];          // row_scale has O elements
    int I = in_sizes[1] / O;      // weight is O*I
    int M = in_sizes[0] / I;      // x is (B*S)*I
    const int D = 8;
    int n_groups = O * I / D;

    size_t off = 0;
    _Float16* xh = (_Float16*)d_ws;                off += (size_t)M * I * sizeof(_Float16);
    _Float16* wq = (_Float16*)((char*)d_ws + off);

    static bool attr_set = false;
    if (!attr_set) {
        (void)hipFuncSetAttribute((const void*)gemm_f16_v4,
                                  hipFuncAttributeMaxDynamicSharedMemorySize,
                                  65536);
        attr_set = true;
    }

    int n_x = M * I;
    int n_pq_blocks = n_groups / 256;
    int n_cvt_blocks = (n_x / 4 + 255) / 256;
    pq_cvt_kernel<<<n_pq_blocks + n_cvt_blocks, 256, 0, stream>>>(
        weight, codebook, rowscale, wq, x, xh, n_x, I / D, n_pq_blocks);

    gemm_f16_v4<<<(M / 128) * (O / 128), 256, 65536, stream>>>(
        xh, wq, bias, out, M, O, I);
}